// Round 7
// baseline (543.443 us; speedup 1.0000x reference)
//
#include <hip/hip_runtime.h>
#include <cstdint>
#include <math.h>

// R6: DIAGNOSTIC ROUND #2 (throwaway timing; best-known = R5 @ 146.9 us).
// Model closure from R3/R4: kernels ~52 us, fills+gaps ~94 us fixed.
// Only k_mask has a measured split; remaining levers are 3-8 us each and
// blind levers have 2x returned ~0. This round: differentiated REP
// amplification (scores x8, topk x8, mask x8, nms x16) so ALL FOUR kernels
// surface above the 42-us poison fills in top-5 with true per-kernel
// counters. Bodies byte-identical to verified R5; R4-verified rep pattern
// (idempotent reps, unroll-1 + memory clobber, barrier-safe divergence).
// Expect passed=true absmax=0.0. R7 reverts REP and targets the dominator.

#define REP_SCORES 8
#define REP_TOPK   8
#define REP_MASK   8
#define REP_NMS    16

// Problem constants (from reference)
constexpr int B = 32;
constexpr int M = 5120;          // 32*32*5 anchors
constexpr int C = 80;            // classes
constexpr int K = 1000;          // TOPK

// d_out layout (flat float32, return order): scores | labels | bboxes | keep
constexpr int OFF_SCORE = 0;
constexpr int OFF_LAB   = B * K;            // 32000
constexpr int OFF_BOX   = 2 * B * K;        // 64000
constexpr int OFF_KEEP  = 2 * B * K + 4 * B * K; // 192000

// workspace layout (bytes)
constexpr size_t WS_KEYS     = 0;                                   // B*M u64
constexpr size_t WS_LABELS   = WS_KEYS   + (size_t)B * M * 8;       // B*M int
constexpr size_t WS_SELSC    = WS_LABELS + (size_t)B * M * 4;       // B*K f32
constexpr size_t WS_BOXOFF   = WS_SELSC + (size_t)B * K * 4;        // B*K*4 f32
constexpr size_t WS_MASK     = WS_BOXOFF + (size_t)B * K * 4 * 4;   // B*K*16 u64

// Fast f64 exp (R2, thrice verified absmax 0.0 on this dataset).
__device__ __forceinline__ double exp_fast(double t) {
    constexpr double INVLN2 = 1.4426950408889634074;
    constexpr double LN2HI  = 6.93147180369123816490e-01; // 33 sig bits
    constexpr double LN2LO  = 1.90821492927058770002e-10;
    double kd = rint(t * INVLN2);
    kd = fmin(fmax(kd, -1000.0), 1000.0);    // guard (no-op for valid data)
    int k = (int)kd;
    double r = (t - kd * LN2HI) - kd * LN2LO;   // first sub exact (Sterbenz)
    constexpr double C3 = 1.0/6.0,        C4  = 1.0/24.0,        C5  = 1.0/120.0;
    constexpr double C6 = 1.0/720.0,      C7  = 1.0/5040.0,      C8  = 1.0/40320.0;
    constexpr double C9 = 1.0/362880.0,   C10 = 1.0/3628800.0,   C11 = 1.0/39916800.0;
    constexpr double C12 = 1.0/479001600.0, C13 = 1.0/6227020800.0;
    double s = fma(r, C13, C12);
    s = fma(r, s, C11); s = fma(r, s, C10); s = fma(r, s, C9);
    s = fma(r, s, C8);  s = fma(r, s, C7);  s = fma(r, s, C6);
    s = fma(r, s, C5);  s = fma(r, s, C4);  s = fma(r, s, C3);
    double u = r * r;
    double q = fma(r, s, 0.5);
    double v = fma(u, q, r);
    double p = 1.0 + v;                       // in [0.707, 1.415]
    long long sbits = (long long)(1023 + k) << 52;
    return p * __longlong_as_double(sbits);   // exact 2^k scale
}
__device__ __forceinline__ float expf_cr(float x) {
    return (float)exp_fast((double)x);
}
__device__ __forceinline__ float sigm_np(float x) {
    float e = expf_cr(-x);
    return __fdiv_rn(1.0f, __fadd_rn(1.0f, e));
}

// Kernel 1: numpy-f32 score/label — 8 lanes per anchor.
__global__ void __launch_bounds__(256)
k_scores(const float* __restrict__ conf, const float* __restrict__ cls,
         unsigned long long* __restrict__ keys, int* __restrict__ labels) {
    int b = blockIdx.y;                  // 0..31
    int g0 = blockIdx.x * 32;            // anchor base within batch (grid.x=160)
    int tid = threadIdx.x;               // 0..255 -> 32 anchors x 8 lanes
    __shared__ float s_lds[32];
    int grp = tid >> 3;                  // anchor within block (0..31)
    int j   = tid & 7;                   // numpy column (0..7)
    int m = g0 + grp;
    size_t base = ((size_t)b * M + m) * C + j;
#pragma unroll 1
    for (int rep = 0; rep < REP_SCORES; rep++) {
        if (tid < 32) {                  // batch the 32 sigmoids (1 wave-exp)
            s_lds[tid] = sigm_np(conf[(size_t)b * M + g0 + tid]);
        }
        __syncthreads();
        float x[10];
#pragma unroll
        for (int k = 0; k < 10; k++) x[k] = cls[base + 8 * k];
        float mx = x[0];
#pragma unroll
        for (int k = 1; k < 10; k++) mx = fmaxf(mx, x[k]);
#pragma unroll
        for (int d = 1; d < 8; d <<= 1) mx = fmaxf(mx, __shfl_xor(mx, d, 64));
        float e[10];
#pragma unroll
        for (int k = 0; k < 10; k++) e[k] = expf_cr(__fsub_rn(x[k], mx));
        float r = e[0];
#pragma unroll
        for (int k = 1; k < 10; k++) r = __fadd_rn(r, e[k]);
        float t1  = __fadd_rn(r,  __shfl_xor(r, 1, 64));
        float t2  = __fadd_rn(t1, __shfl_xor(t1, 2, 64));
        float sum = __fadd_rn(t2, __shfl_xor(t2, 4, 64));
        float s = s_lds[grp];
        float best = -1.0f; int bc = 0;
#pragma unroll
        for (int k = 0; k < 10; k++) {
            float q = __fdiv_rn(e[k], sum);
            float p = __fmul_rn(s, q);
            if (p > best) { best = p; bc = 8 * k + j; }   // k asc => first max
        }
#pragma unroll
        for (int d = 1; d < 8; d <<= 1) {    // lattice max on (p, -c)
            float op = __shfl_xor(best, d, 64);
            int   oc = __shfl_xor(bc,   d, 64);
            if (op > best || (op == best && oc < bc)) { best = op; bc = oc; }
        }
        if (j == 0) {
            keys[(size_t)b * M + m] =
                ((unsigned long long)__float_as_uint(best) << 32) |
                (unsigned long long)(0xFFFFFFFFu - (unsigned)m);
            labels[(size_t)b * M + m] = bc;
        }
        __syncthreads();                 // next rep rewrites s_lds
        asm volatile("" ::: "memory");   // defeat cross-rep hoist/merge
    }
}

// Decode one selected box (numpy-f32 op order) and write all its outputs.
__device__ __forceinline__ void decode_write(
    int b, int rank, int m, float score, int lab,
    const float* __restrict__ reg, const float* __restrict__ anchors,
    float* __restrict__ out, float4* __restrict__ boxes_off,
    float* __restrict__ sel_score)
{
    float4 r = ((const float4*)reg)[(size_t)b * M + m];
    float4 a = ((const float4*)anchors)[m];
    float cx = __fadd_rn(__fmul_rn(sigm_np(r.x), 16.0f), a.x);
    float cy = __fadd_rn(__fmul_rn(sigm_np(r.y), 16.0f), a.y);
    float w  = __fmul_rn(expf_cr(r.z), a.z);
    float h  = __fmul_rn(expf_cr(r.w), a.w);
    float x1 = __fdiv_rn(__fsub_rn(cx, __fmul_rn(0.5f, w)), 512.0f);
    float y1 = __fdiv_rn(__fsub_rn(cy, __fmul_rn(0.5f, h)), 512.0f);
    float x2 = __fdiv_rn(__fadd_rn(cx, __fmul_rn(0.5f, w)), 512.0f);
    float y2 = __fdiv_rn(__fadd_rn(cy, __fmul_rn(0.5f, h)), 512.0f);
    x1 = fminf(fmaxf(x1, 0.0f), 1.0f);
    y1 = fminf(fmaxf(y1, 0.0f), 1.0f);
    x2 = fminf(fmaxf(x2, 0.0f), 1.0f);
    y2 = fminf(fmaxf(y2, 0.0f), 1.0f);
    ((float4*)(out + OFF_BOX))[b * K + rank] = make_float4(x1, y1, x2, y2);
    out[OFF_LAB + b * K + rank] = (float)lab;
    float off = __fmul_rn(2.0f, (float)lab);
    boxes_off[b * K + rank] = make_float4(__fadd_rn(x1, off), __fadd_rn(y1, off),
                                          __fadd_rn(x2, off), __fadd_rn(y2, off));
    sel_score[b * K + rank] = score;
}

// Register-bitonic compare-exchange (pair within wave, jsz<=32).
__device__ __forceinline__ void cx_reg(unsigned long long& v, int i, int jsz, int ksz) {
    unsigned long long vp = __shfl_xor(v, jsz, 64);
    bool takeMax = (((i & ksz) == 0) == ((i & jsz) == 0));
    v = takeMax ? (vp > v ? vp : v) : (vp < v ? vp : v);
}

// Kernel 2: exact top-K via histogram-select + bitonic sort (R1 structure).
__global__ void __launch_bounds__(1024)
k_topk(const unsigned long long* __restrict__ keys,
       const int* __restrict__ labels,
       const float* __restrict__ reg, const float* __restrict__ anchors,
       float* __restrict__ out, float4* __restrict__ boxes_off,
       float* __restrict__ sel_score) {
    int b = blockIdx.x;                  // grid = 32
    int tid = threadIdx.x;               // block = 1024
    int lane = tid & 63;
    int wv   = tid >> 6;                 // 16 waves
    const unsigned long long* kb = keys + (size_t)b * M;

    __shared__ unsigned int hist[2048];
    __shared__ unsigned long long cand[2048];   // 16 KB
    __shared__ unsigned int waveSuf[17];
    __shared__ int scnt, thrBin, ovf;

#pragma unroll 1
    for (int rep = 0; rep < REP_TOPK; rep++) {
        for (int i = tid; i < 2048; i += 1024) hist[i] = 0;
        if (tid == 0) { scnt = 0; ovf = 0; }
        __syncthreads();

        unsigned long long k5[5];
#pragma unroll
        for (int i = 0; i < 5; i++) {
            k5[i] = kb[tid + i * 1024];              // coalesced
            atomicAdd(&hist[(unsigned)(k5[i] >> 51)], 1u);
        }
        __syncthreads();

        // ---- hierarchical suffix scan for the threshold bin ----
        unsigned h0 = hist[2 * tid], h1 = hist[2 * tid + 1];
        unsigned pr = h0 + h1;
        unsigned s = pr;
#pragma unroll
        for (int d = 1; d < 64; d <<= 1) {
            unsigned o = __shfl_down(s, d, 64);
            if (lane + d < 64) s += o;
        }
        if (lane == 0) waveSuf[wv] = s;
        if (tid == 0) waveSuf[16] = 0;
        __syncthreads();
        if (wv == 0) {
            unsigned t = (lane < 16) ? waveSuf[lane] : 0u;
#pragma unroll
            for (int d = 1; d < 16; d <<= 1) {
                unsigned o = __shfl_down(t, d, 64);
                if (lane + d < 64) t += o;
            }
            if (lane < 16) waveSuf[lane] = t;
        }
        __syncthreads();
        {
            unsigned aboveWave = waveSuf[wv + 1];
            unsigned aboveLane = s - pr;
            unsigned suf1 = aboveWave + aboveLane + h1;
            unsigned suf0 = suf1 + h0;
            if (suf0 >= (unsigned)K && suf0 - h0 < (unsigned)K) thrBin = 2 * tid;
            if (suf1 >= (unsigned)K && suf1 - h1 < (unsigned)K) thrBin = 2 * tid + 1;
        }
        __syncthreads();
        int T = thrBin;
#pragma unroll
        for (int i = 0; i < 5; i++) {
            if ((int)(k5[i] >> 51) >= T) {
                int pos = atomicAdd(&scnt, 1);
                if (pos < 2048) cand[pos] = k5[i]; else ovf = 1;
            }
        }
        __syncthreads();
        if (!ovf) {
            int S = scnt;
            int N = (S <= 1024) ? 1024 : 2048;
            for (int i = tid; i < 2048; i += 1024)
                if (i >= S) cand[i] = 0ull;
            __syncthreads();
            bool act = (128 * wv < N);
            int i0 = 128 * wv + lane, i1 = i0 + 64;
            unsigned long long v0 = 0ull, v1 = 0ull;
            if (act) { v0 = cand[i0]; v1 = cand[i1]; }
            if (act) {
#pragma unroll
                for (int ksz = 2; ksz <= 64; ksz <<= 1)
#pragma unroll
                    for (int jsz = ksz >> 1; jsz > 0; jsz >>= 1) {
                        cx_reg(v0, i0, jsz, ksz);
                        cx_reg(v1, i1, jsz, ksz);
                    }
                cand[i0] = v0; cand[i1] = v1;
            }
            __syncthreads();
            for (int ksz = 128; ksz <= N; ksz <<= 1) {
                for (int jsz = ksz >> 1; jsz >= 64; jsz >>= 1) {
                    if (tid < (N >> 1)) {
                        int i = 2 * tid - (tid & (jsz - 1));
                        unsigned long long a = cand[i], c = cand[i + jsz];
                        bool desc = ((i & ksz) == 0);
                        if ((a < c) == desc) { cand[i] = c; cand[i + jsz] = a; }
                    }
                    __syncthreads();
                }
                if (act) {
                    v0 = cand[i0]; v1 = cand[i1];
#pragma unroll
                    for (int jsz = 32; jsz > 0; jsz >>= 1) {
                        cx_reg(v0, i0, jsz, ksz);
                        cx_reg(v1, i1, jsz, ksz);
                    }
                    cand[i0] = v0; cand[i1] = v1;
                }
                __syncthreads();
            }
            if (tid < K) {
                unsigned long long key = cand[tid];
                int mm = (int)(0xFFFFFFFFu - (unsigned)(key & 0xFFFFFFFFu));
                float sc = __uint_as_float((unsigned)(key >> 32));
                int lab = labels[(size_t)b * M + mm];
                decode_write(b, tid, mm, sc, lab, reg, anchors, out, boxes_off, sel_score);
            }
        } else {
            // exact fallback (never expected for this data)
#pragma unroll
            for (int i = 0; i < 5; i++) {
                unsigned long long my = k5[i];
                int rank = 0;
                for (int j = 0; j < M; j++) rank += (kb[j] > my) ? 1 : 0;
                if (rank < K) {
                    int mm = tid + i * 1024;
                    float sc = __uint_as_float((unsigned)(my >> 32));
                    int lab = labels[(size_t)b * M + mm];
                    decode_write(b, rank, mm, sc, lab, reg, anchors, out, boxes_off, sel_score);
                }
            }
        }
        __syncthreads();                 // isolate reps
        asm volatile("" ::: "memory");
    }
}

// Kernel 3 v2 (R5, verified): dense lower-triangle packing, wave-private
// LDS j-tile, exact f64 midpoint IoU test. REP-wrapped: no early return
// (rowOk guards compute only) so the barrier stays convergent.
__global__ void __launch_bounds__(256)
k_mask(const float4* __restrict__ boxes_off,
       unsigned long long* __restrict__ mask) {
    int b    = blockIdx.y;               // 0..31
    int wv   = threadIdx.x >> 6;         // 0..3
    int lane = threadIdx.x & 63;
    int p = blockIdx.x * 4 + wv;         // 0..135 word-tile index
    // triangular decode: largest r with r(r+1)/2 <= p (+ integer fixup)
    int r = (int)((sqrtf((float)(8 * p + 1)) - 1.0f) * 0.5f);
    int tri = (r * (r + 1)) >> 1;
    if (tri > p)          { r -= 1; tri = (r * (r + 1)) >> 1; }
    else if (p - tri > r) { r += 1; tri = (r * (r + 1)) >> 1; }
    int W = p - tri;                     // 0..r

    __shared__ float4 sj[4][64];
    __shared__ float  sa[4][64];
    int j = W * 64 + lane;
    int i = r * 64 + lane;
    bool rowOk = (i < K);
    constexpr double MID = (double)0.6f + 0x1.0p-25;   // exact midpoint test
#pragma unroll 1
    for (int rep = 0; rep < REP_MASK; rep++) {
        float4 bx = (j < K) ? boxes_off[b * K + j]
                            : make_float4(3e30f, 3e30f, -3e30f, -3e30f);
        sj[wv][lane] = bx;
        sa[wv][lane] = __fmul_rn(__fsub_rn(bx.z, bx.x), __fsub_rn(bx.w, bx.y));
        float4 bi = make_float4(0.f, 0.f, 0.f, 0.f);
        float ai = 0.f;
        if (rowOk) {
            bi = boxes_off[b * K + i];
            ai = __fmul_rn(__fsub_rn(bi.z, bi.x), __fsub_rn(bi.w, bi.y));
        }
        __syncthreads();
        if (rowOk) {
            unsigned long long bits = 0ull;
#pragma unroll 8
            for (int jj = 0; jj < 64; jj++) {
                float4 bj = sj[wv][jj];          // wave-uniform -> broadcast
                float aj = sa[wv][jj];
                float xx1 = fmaxf(bi.x, bj.x), yy1 = fmaxf(bi.y, bj.y);
                float xx2 = fminf(bi.z, bj.z), yy2 = fminf(bi.w, bj.w);
                float ww = fmaxf(1e-28f, __fsub_rn(xx2, xx1));
                float hh = fmaxf(1e-28f, __fsub_rn(yy2, yy1));
                float inter = __fmul_rn(ww, hh);
                float denom = __fadd_rn(__fsub_rn(__fadd_rn(ai, aj), inter), 1e-14f);
                if ((double)inter > MID * (double)denom) bits |= (1ull << jj);
            }
            mask[((size_t)b * K + i) * 16 + W] = bits;
        }
        __syncthreads();                 // next rep rewrites sj/sa
        asm volatile("" ::: "memory");
    }
}

// Kernel 4: exact NMS via bracketed Jacobi fixed point.
__global__ void __launch_bounds__(1024)
k_nms(const unsigned long long* __restrict__ mask,
      const float* __restrict__ sel_score,
      float* __restrict__ out) {
    int b = blockIdx.x;
    int j = threadIdx.x;                 // 0..1023
    int w = j >> 6;                      // wave index == keep-word index
    int jb = j & 63;
    __shared__ unsigned long long U[16], L[16];
    __shared__ int flag[2];
#pragma unroll 1
    for (int rep = 0; rep < REP_NMS; rep++) {
        unsigned long long rw[16];
        if (j < K) {
            const ulonglong2* rp2 =
                (const ulonglong2*)(mask + ((size_t)b * K + j) * 16);
#pragma unroll
            for (int t = 0; t < 8; t++) {
                ulonglong2 v = rp2[t];
                rw[2 * t] = v.x; rw[2 * t + 1] = v.y;
            }
#pragma unroll
            for (int t = 0; t < 16; t++) {
                unsigned long long bm =
                    (t < w) ? ~0ull
                            : ((t == w && jb != 0) ? ((1ull << jb) - 1ull) : 0ull);
                rw[t] &= bm;                 // only i<j can suppress j
            }
        } else {
#pragma unroll
            for (int t = 0; t < 16; t++) rw[t] = 0ull;
        }
        if (j < 16) { U[j] = (j < 15) ? ~0ull : ((1ull << 40) - 1); L[j] = 0ull; }
        if (j == 0) { flag[0] = 0; flag[1] = 0; }
        __syncthreads();
        for (int k = 0; k < 1025; k++) {
            unsigned long long supU = 0ull, supL = 0ull;
#pragma unroll
            for (int t = 0; t < 16; t++) {
                unsigned long long Ut = U[t], Lt = L[t];   // broadcast
                supU |= Lt & rw[t];   // new U = f(L)
                supL |= Ut & rw[t];   // new L = f(U)
            }
            bool nu = (j < K) && (supU == 0ull);
            bool nl = (j < K) && (supL == 0ull);
            __syncthreads();                 // all reads of old U/L done
            unsigned long long bu = __ballot(nu);
            unsigned long long bl = __ballot(nl);
            if (jb == 0) {
                U[w] = bu; L[w] = bl;
                if (bu != bl) flag[k & 1] = 1;
            }
            if (j == 0) flag[(k + 1) & 1] = 0;
            __syncthreads();
            if (flag[k & 1] == 0) break;     // uniform exit; U==L == exact keep
        }
        if (j < K) {
            bool kp = ((U[w] >> jb) & 1ull) != 0ull;
            float s = sel_score[b * K + j];
            kp = kp && (s >= 0.05f);
            out[OFF_SCORE + b * K + j] = kp ? s : 0.0f;
            out[OFF_KEEP + b * K + j]  = kp ? 1.0f : 0.0f;
        }
        __syncthreads();                 // next rep re-inits U/L
        asm volatile("" ::: "memory");
    }
}

extern "C" void kernel_launch(void* const* d_in, const int* in_sizes, int n_in,
                              void* d_out, int out_size, void* d_ws, size_t ws_size,
                              hipStream_t stream) {
    const float* conf    = (const float*)d_in[0];
    const float* cls     = (const float*)d_in[1];
    const float* reg     = (const float*)d_in[2];
    const float* anchors = (const float*)d_in[3];
    float* out = (float*)d_out;
    char* ws = (char*)d_ws;

    unsigned long long* keys = (unsigned long long*)(ws + WS_KEYS);
    int*    labels   = (int*)(ws + WS_LABELS);
    float*  sel_sc   = (float*)(ws + WS_SELSC);
    float4* boxes_off = (float4*)(ws + WS_BOXOFF);
    unsigned long long* mask = (unsigned long long*)(ws + WS_MASK);

    k_scores<<<dim3(160, B), 256, 0, stream>>>(conf, cls, keys, labels);
    k_topk  <<<B, 1024, 0, stream>>>(keys, labels, reg, anchors, out, boxes_off, sel_sc);
    k_mask  <<<dim3(34, B), 256, 0, stream>>>(boxes_off, mask);
    k_nms   <<<32, 1024, 0, stream>>>(mask, sel_sc, out);
}

// Round 8
// 150.256 us; speedup vs baseline: 3.6168x; 3.6168x over previous
//
#include <hip/hip_runtime.h>
#include <cstdint>
#include <math.h>

// R7: k_topk v3 + decode relocation (one architectural lever).
// R6 split: k_topk 18.5 us dominant (95% stall, 32 blocks, ~40 barrier
// rounds); k_mask ~14, k_scores <18.5, k_nms <9.3; fills+gaps ~94 fixed.
// v3: (a) two-level radix threshold refinement -> candidate set S<=1024
// always (exact top-K superset, proof in comments), so the sort is N=1024
// one-elem-per-thread (10 light LDS substeps + 45 single-shfl substeps;
// was 15 heavy + 26 double). (b) decode moved out: k_topk emits sorted
// keys (skeys) + labels only; k_mask decodes its 128 boxes per wave
// redundantly (bit-identical op sequence, ~1 us chip-wide, kills the
// boxes_off round-trip); k_nms decodes box j for the bboxes output with
// loads hoisted above the Jacobi loop (latency hidden) and reads scores
// from skeys. Prediction: 146.9 -> ~140, absmax 0.0.

// Problem constants (from reference)
constexpr int B = 32;
constexpr int M = 5120;          // 32*32*5 anchors
constexpr int C = 80;            // classes
constexpr int K = 1000;          // TOPK

// d_out layout (flat float32, return order): scores | labels | bboxes | keep
constexpr int OFF_SCORE = 0;
constexpr int OFF_LAB   = B * K;            // 32000
constexpr int OFF_BOX   = 2 * B * K;        // 64000
constexpr int OFF_KEEP  = 2 * B * K + 4 * B * K; // 192000

// workspace layout (bytes)
constexpr size_t WS_KEYS   = 0;                                  // B*M u64
constexpr size_t WS_LABELS = WS_KEYS   + (size_t)B * M * 8;      // B*M int
constexpr size_t WS_SKEYS  = WS_LABELS + (size_t)B * M * 4;      // B*K u64
constexpr size_t WS_MASK   = WS_SKEYS  + (size_t)B * K * 8;      // B*K*16 u64

// Fast f64 exp (R2, thrice verified absmax 0.0 on this dataset).
__device__ __forceinline__ double exp_fast(double t) {
    constexpr double INVLN2 = 1.4426950408889634074;
    constexpr double LN2HI  = 6.93147180369123816490e-01; // 33 sig bits
    constexpr double LN2LO  = 1.90821492927058770002e-10;
    double kd = rint(t * INVLN2);
    kd = fmin(fmax(kd, -1000.0), 1000.0);    // guard (no-op for valid data)
    int k = (int)kd;
    double r = (t - kd * LN2HI) - kd * LN2LO;   // first sub exact (Sterbenz)
    constexpr double C3 = 1.0/6.0,        C4  = 1.0/24.0,        C5  = 1.0/120.0;
    constexpr double C6 = 1.0/720.0,      C7  = 1.0/5040.0,      C8  = 1.0/40320.0;
    constexpr double C9 = 1.0/362880.0,   C10 = 1.0/3628800.0,   C11 = 1.0/39916800.0;
    constexpr double C12 = 1.0/479001600.0, C13 = 1.0/6227020800.0;
    double s = fma(r, C13, C12);
    s = fma(r, s, C11); s = fma(r, s, C10); s = fma(r, s, C9);
    s = fma(r, s, C8);  s = fma(r, s, C7);  s = fma(r, s, C6);
    s = fma(r, s, C5);  s = fma(r, s, C4);  s = fma(r, s, C3);
    double u = r * r;
    double q = fma(r, s, 0.5);
    double v = fma(u, q, r);
    double p = 1.0 + v;                       // in [0.707, 1.415]
    long long sbits = (long long)(1023 + k) << 52;
    return p * __longlong_as_double(sbits);   // exact 2^k scale
}
__device__ __forceinline__ float expf_cr(float x) {
    return (float)exp_fast((double)x);
}
__device__ __forceinline__ float sigm_np(float x) {
    float e = expf_cr(-x);
    return __fdiv_rn(1.0f, __fadd_rn(1.0f, e));
}

// Decode box m of batch b: numpy-f32 op order, identical to the verified
// decode_write sequence (bit-identical results wherever recomputed).
__device__ __forceinline__ float4 decode_box(
    int b, int m, const float* __restrict__ reg, const float* __restrict__ anchors) {
    float4 r = ((const float4*)reg)[(size_t)b * M + m];
    float4 a = ((const float4*)anchors)[m];
    float cx = __fadd_rn(__fmul_rn(sigm_np(r.x), 16.0f), a.x);
    float cy = __fadd_rn(__fmul_rn(sigm_np(r.y), 16.0f), a.y);
    float w  = __fmul_rn(expf_cr(r.z), a.z);
    float h  = __fmul_rn(expf_cr(r.w), a.w);
    float x1 = __fdiv_rn(__fsub_rn(cx, __fmul_rn(0.5f, w)), 512.0f);
    float y1 = __fdiv_rn(__fsub_rn(cy, __fmul_rn(0.5f, h)), 512.0f);
    float x2 = __fdiv_rn(__fadd_rn(cx, __fmul_rn(0.5f, w)), 512.0f);
    float y2 = __fdiv_rn(__fadd_rn(cy, __fmul_rn(0.5f, h)), 512.0f);
    x1 = fminf(fmaxf(x1, 0.0f), 1.0f);
    y1 = fminf(fmaxf(y1, 0.0f), 1.0f);
    x2 = fminf(fmaxf(x2, 0.0f), 1.0f);
    y2 = fminf(fmaxf(y2, 0.0f), 1.0f);
    return make_float4(x1, y1, x2, y2);
}

// Kernel 1: numpy-f32 score/label — 8 lanes per anchor (verified R5 body).
__global__ void __launch_bounds__(256)
k_scores(const float* __restrict__ conf, const float* __restrict__ cls,
         unsigned long long* __restrict__ keys, int* __restrict__ labels) {
    int b = blockIdx.y;                  // 0..31
    int g0 = blockIdx.x * 32;            // anchor base within batch (grid.x=160)
    int tid = threadIdx.x;               // 0..255 -> 32 anchors x 8 lanes
    __shared__ float s_lds[32];
    if (tid < 32) {                      // batch the 32 sigmoids (1 wave-exp)
        s_lds[tid] = sigm_np(conf[(size_t)b * M + g0 + tid]);
    }
    __syncthreads();
    int grp = tid >> 3;                  // anchor within block (0..31)
    int j   = tid & 7;                   // numpy column (0..7)
    int m = g0 + grp;
    size_t base = ((size_t)b * M + m) * C + j;
    float x[10];
#pragma unroll
    for (int k = 0; k < 10; k++) x[k] = cls[base + 8 * k];
    float mx = x[0];
#pragma unroll
    for (int k = 1; k < 10; k++) mx = fmaxf(mx, x[k]);
#pragma unroll
    for (int d = 1; d < 8; d <<= 1) mx = fmaxf(mx, __shfl_xor(mx, d, 64));
    float e[10];
#pragma unroll
    for (int k = 0; k < 10; k++) e[k] = expf_cr(__fsub_rn(x[k], mx));
    float r = e[0];
#pragma unroll
    for (int k = 1; k < 10; k++) r = __fadd_rn(r, e[k]);
    float t1  = __fadd_rn(r,  __shfl_xor(r, 1, 64));
    float t2  = __fadd_rn(t1, __shfl_xor(t1, 2, 64));
    float sum = __fadd_rn(t2, __shfl_xor(t2, 4, 64));
    float s = s_lds[grp];
    float best = -1.0f; int bc = 0;
#pragma unroll
    for (int k = 0; k < 10; k++) {
        float q = __fdiv_rn(e[k], sum);
        float p = __fmul_rn(s, q);
        if (p > best) { best = p; bc = 8 * k + j; }   // k asc => first max
    }
#pragma unroll
    for (int d = 1; d < 8; d <<= 1) {    // lattice max on (p, -c)
        float op = __shfl_xor(best, d, 64);
        int   oc = __shfl_xor(bc,   d, 64);
        if (op > best || (op == best && oc < bc)) { best = op; bc = oc; }
    }
    if (j == 0) {
        keys[(size_t)b * M + m] =
            ((unsigned long long)__float_as_uint(best) << 32) |
            (unsigned long long)(0xFFFFFFFFu - (unsigned)m);
        labels[(size_t)b * M + m] = bc;
    }
}

// Register-bitonic compare-exchange (partner within wave, jsz<=32).
__device__ __forceinline__ void cx_reg(unsigned long long& v, int i, int jsz, int ksz) {
    unsigned long long vp = __shfl_xor(v, jsz, 64);
    bool takeMax = (((i & ksz) == 0) == ((i & jsz) == 0));
    v = takeMax ? (vp > v ? vp : v) : (vp < v ? vp : v);
}

// Kernel 2 v3: exact top-K. Two-level radix threshold (S<=1024 virtually
// always) + N=1024 one-elem-per-thread bitonic (reg substeps via shfl,
// cross-wave via light LDS). Outputs: sorted keys skeys[b*K+rank] and
// out[labels]. No decode here (moved to k_mask / k_nms).
// Selection exactness: refined predicate excludes only keys with
// (bin < T1) or (bin == T1 && subbin < T2); every such key is u64-less
// than every included key, and included count S2 >= K, so the top-K of
// the included set == global top-K.
__global__ void __launch_bounds__(1024)
k_topk(const unsigned long long* __restrict__ keys,
       const int* __restrict__ labels,
       unsigned long long* __restrict__ skeys,
       float* __restrict__ out) {
    int b = blockIdx.x;                  // grid = 32
    int tid = threadIdx.x;               // block = 1024
    int lane = tid & 63;
    int wv   = tid >> 6;                 // 16 waves
    const unsigned long long* kb = keys + (size_t)b * M;

    __shared__ unsigned int hist[2048];
    __shared__ unsigned long long cand[1024];   // 8 KB
    __shared__ unsigned int waveSuf[17];
    __shared__ int scnt, thrBin, thrBin2, sA, sH, sS2, ovf;

    for (int i = tid; i < 2048; i += 1024) hist[i] = 0;
    if (tid == 0) { scnt = 0; ovf = 0; }
    __syncthreads();

    unsigned long long k5[5];
#pragma unroll
    for (int i = 0; i < 5; i++) {
        k5[i] = kb[tid + i * 1024];              // coalesced
        atomicAdd(&hist[(unsigned)(k5[i] >> 51)], 1u);
    }
    __syncthreads();

    // ---- level-1 hierarchical suffix scan (top 13 key bits; bins<2048
    // since score<1 => exponent<=126) ----
    {
        unsigned h0 = hist[2 * tid], h1 = hist[2 * tid + 1];
        unsigned pr = h0 + h1;
        unsigned s = pr;
#pragma unroll
        for (int d = 1; d < 64; d <<= 1) {
            unsigned o = __shfl_down(s, d, 64);
            if (lane + d < 64) s += o;
        }
        if (lane == 0) waveSuf[wv] = s;
        if (tid == 0) waveSuf[16] = 0;
        __syncthreads();
        if (wv == 0) {
            unsigned t = (lane < 16) ? waveSuf[lane] : 0u;
#pragma unroll
            for (int d = 1; d < 16; d <<= 1) {
                unsigned o = __shfl_down(t, d, 64);
                if (lane + d < 64) t += o;
            }
            if (lane < 16) waveSuf[lane] = t;
        }
        __syncthreads();
        unsigned aboveWave = waveSuf[wv + 1];
        unsigned aboveLane = s - pr;
        unsigned suf1 = aboveWave + aboveLane + h1;
        unsigned suf0 = suf1 + h0;
        // unique crossing; crossing thread also records A (count strictly
        // above bin T1) and H (bin T1 size)
        if (suf0 >= (unsigned)K && suf0 - h0 < (unsigned)K) {
            thrBin = 2 * tid; sA = (int)(suf0 - h0); sH = (int)h0;
        }
        if (suf1 >= (unsigned)K && suf1 - h1 < (unsigned)K) {
            thrBin = 2 * tid + 1; sA = (int)(suf1 - h1); sH = (int)h1;
        }
    }
    __syncthreads();
    int T1 = thrBin, A = sA, H = sH;
    bool refined = (A + H > 1024);
    int T2 = 0;

    if (refined) {
        // ---- level-2: histogram bin-T1 members on key bits 50..40 ----
        for (int i = tid; i < 2048; i += 1024) hist[i] = 0;
        __syncthreads();
#pragma unroll
        for (int i = 0; i < 5; i++)
            if ((int)(k5[i] >> 51) == T1)
                atomicAdd(&hist[(unsigned)((k5[i] >> 40) & 2047)], 1u);
        __syncthreads();
        unsigned KK = (unsigned)(K - A);          // >0 since A<K
        unsigned g0 = hist[2 * tid], g1 = hist[2 * tid + 1];
        unsigned pr = g0 + g1;
        unsigned s = pr;
#pragma unroll
        for (int d = 1; d < 64; d <<= 1) {
            unsigned o = __shfl_down(s, d, 64);
            if (lane + d < 64) s += o;
        }
        if (lane == 0) waveSuf[wv] = s;
        if (tid == 0) waveSuf[16] = 0;
        __syncthreads();
        if (wv == 0) {
            unsigned t = (lane < 16) ? waveSuf[lane] : 0u;
#pragma unroll
            for (int d = 1; d < 16; d <<= 1) {
                unsigned o = __shfl_down(t, d, 64);
                if (lane + d < 64) t += o;
            }
            if (lane < 16) waveSuf[lane] = t;
        }
        __syncthreads();
        unsigned aboveWave = waveSuf[wv + 1];
        unsigned aboveLane = s - pr;
        unsigned suf1 = aboveWave + aboveLane + g1;
        unsigned suf0 = suf1 + g0;
        if (suf0 >= KK && suf0 - g0 < KK) { thrBin2 = 2 * tid;     sS2 = A + (int)suf0; }
        if (suf1 >= KK && suf1 - g1 < KK) { thrBin2 = 2 * tid + 1; sS2 = A + (int)suf1; }
        __syncthreads();
        T2 = thrBin2;
    }

    // ---- collect candidates ----
#pragma unroll
    for (int i = 0; i < 5; i++) {
        int bin = (int)(k5[i] >> 51);
        bool sel = refined
                 ? (bin > T1 || (bin == T1 && (int)((k5[i] >> 40) & 2047) >= T2))
                 : (bin >= T1);
        if (sel) {
            int pos = atomicAdd(&scnt, 1);
            if (pos < 1024) cand[pos] = k5[i]; else ovf = 1;
        }
    }
    __syncthreads();

    if (!ovf) {
        int S = scnt;                        // K <= S <= 1024
        if (tid >= S) cand[tid] = 0ull;      // pad sorts below real keys (>0)
        __syncthreads();
        unsigned long long v = cand[tid];    // element index == tid
        // stages ksz=2..64: intra-wave, pure registers, 0 barriers
#pragma unroll
        for (int ksz = 2; ksz <= 64; ksz <<= 1)
#pragma unroll
            for (int jsz = ksz >> 1; jsz > 0; jsz >>= 1)
                cx_reg(v, tid, jsz, ksz);
        // stages ksz=128..1024: jsz>=64 via LDS exchange, jsz<=32 registers
        for (int ksz = 128; ksz <= 1024; ksz <<= 1) {
            for (int jsz = ksz >> 1; jsz >= 64; jsz >>= 1) {
                cand[tid] = v;
                __syncthreads();
                unsigned long long vp = cand[tid ^ jsz];
                bool takeMax = (((tid & ksz) == 0) == ((tid & jsz) == 0));
                v = takeMax ? (vp > v ? vp : v) : (vp < v ? vp : v);
                __syncthreads();
            }
#pragma unroll
            for (int jsz = 32; jsz > 0; jsz >>= 1)
                cx_reg(v, tid, jsz, ksz);
        }
        if (tid < K) {                       // v = key of rank tid
            int mm = (int)(0xFFFFFFFFu - (unsigned)(v & 0xFFFFFFFFu));
            skeys[(size_t)b * K + tid] = v;
            out[OFF_LAB + b * K + tid] = (float)labels[(size_t)b * M + mm];
        }
    } else {
        // exact fallback (never expected): O(M) rank per key
#pragma unroll
        for (int i = 0; i < 5; i++) {
            unsigned long long my = k5[i];
            int rank = 0;
            for (int j = 0; j < M; j++) rank += (kb[j] > my) ? 1 : 0;
            if (rank < K) {
                int mm = tid + i * 1024;
                skeys[(size_t)b * K + rank] = my;
                out[OFF_LAB + b * K + rank] = (float)labels[(size_t)b * M + mm];
            }
        }
    }
}

// Kernel 3 v3: suppression bitmask. Dense lower-triangle packing (R5) +
// per-wave redundant decode from skeys (no boxes_off round-trip). Exact
// f64 midpoint IoU test (R5). Decode op sequence bit-identical everywhere.
__global__ void __launch_bounds__(256)
k_mask(const unsigned long long* __restrict__ skeys,
       const int* __restrict__ labels,
       const float* __restrict__ reg, const float* __restrict__ anchors,
       unsigned long long* __restrict__ mask) {
    int b    = blockIdx.y;               // 0..31
    int wv   = threadIdx.x >> 6;         // 0..3
    int lane = threadIdx.x & 63;
    int p = blockIdx.x * 4 + wv;         // 0..135 word-tile index
    // triangular decode: largest r with r(r+1)/2 <= p (+ integer fixup)
    int r = (int)((sqrtf((float)(8 * p + 1)) - 1.0f) * 0.5f);
    int tri = (r * (r + 1)) >> 1;
    if (tri > p)          { r -= 1; tri = (r * (r + 1)) >> 1; }
    else if (p - tri > r) { r += 1; tri = (r * (r + 1)) >> 1; }
    int W = p - tri;                     // 0..r

    __shared__ float4 sj[4][64];
    __shared__ float  sa[4][64];
    int j = W * 64 + lane;
    float4 bj = make_float4(3e30f, 3e30f, -3e30f, -3e30f);   // pad
    if (j < K) {
        unsigned long long sk = skeys[(size_t)b * K + j];
        int m = (int)(0xFFFFFFFFu - (unsigned)(sk & 0xFFFFFFFFu));
        float off = __fmul_rn(2.0f, (float)labels[(size_t)b * M + m]);
        float4 bb = decode_box(b, m, reg, anchors);
        bj = make_float4(__fadd_rn(bb.x, off), __fadd_rn(bb.y, off),
                         __fadd_rn(bb.z, off), __fadd_rn(bb.w, off));
    }
    sj[wv][lane] = bj;
    sa[wv][lane] = __fmul_rn(__fsub_rn(bj.z, bj.x), __fsub_rn(bj.w, bj.y));
    int i = r * 64 + lane;
    bool rowOk = (i < K);
    float4 bi = make_float4(0.f, 0.f, 0.f, 0.f);
    float ai = 0.f;
    if (rowOk) {
        unsigned long long sk = skeys[(size_t)b * K + i];
        int m = (int)(0xFFFFFFFFu - (unsigned)(sk & 0xFFFFFFFFu));
        float off = __fmul_rn(2.0f, (float)labels[(size_t)b * M + m]);
        float4 bb = decode_box(b, m, reg, anchors);
        bi = make_float4(__fadd_rn(bb.x, off), __fadd_rn(bb.y, off),
                         __fadd_rn(bb.z, off), __fadd_rn(bb.w, off));
        ai = __fmul_rn(__fsub_rn(bi.z, bi.x), __fsub_rn(bi.w, bi.y));
    }
    __syncthreads();
    if (!rowOk) return;
    // RN(inter/denom) > 0.6f <=> (double)inter > MID*(double)denom (exact;
    // MID = midpoint of [0.6f, succ(0.6f)], tie rounds to even = 0.6f).
    constexpr double MID = (double)0.6f + 0x1.0p-25;
    unsigned long long bits = 0ull;
#pragma unroll 8
    for (int jj = 0; jj < 64; jj++) {
        float4 bj2 = sj[wv][jj];         // wave-uniform -> broadcast
        float aj = sa[wv][jj];
        float xx1 = fmaxf(bi.x, bj2.x), yy1 = fmaxf(bi.y, bj2.y);
        float xx2 = fminf(bi.z, bj2.z), yy2 = fminf(bi.w, bj2.w);
        float ww = fmaxf(1e-28f, __fsub_rn(xx2, xx1));
        float hh = fmaxf(1e-28f, __fsub_rn(yy2, yy1));
        float inter = __fmul_rn(ww, hh);
        float denom = __fadd_rn(__fsub_rn(__fadd_rn(ai, aj), inter), 1e-14f);
        if ((double)inter > MID * (double)denom) bits |= (1ull << jj);
    }
    mask[((size_t)b * K + i) * 16 + W] = bits;
}

// Kernel 4 v3: exact NMS (bracketed Jacobi fixed point) + bboxes-output
// decode fused (loads issued before the Jacobi loop; latency hidden).
__global__ void __launch_bounds__(1024)
k_nms(const unsigned long long* __restrict__ mask,
      const unsigned long long* __restrict__ skeys,
      const float* __restrict__ reg, const float* __restrict__ anchors,
      float* __restrict__ out) {
    int b = blockIdx.x;
    int j = threadIdx.x;                 // 0..1023
    int w = j >> 6;                      // wave index == keep-word index
    int jb = j & 63;
    __shared__ unsigned long long U[16], L[16];
    __shared__ int flag[2];
    unsigned long long rw[16];
    float s = 0.0f;
    float4 bb = make_float4(0.f, 0.f, 0.f, 0.f);
    if (j < K) {
        unsigned long long sk = skeys[(size_t)b * K + j];
        s = __uint_as_float((unsigned)(sk >> 32));
        int m = (int)(0xFFFFFFFFu - (unsigned)(sk & 0xFFFFFFFFu));
        bb = decode_box(b, m, reg, anchors);   // loads hoisted above Jacobi
        const ulonglong2* rp2 =
            (const ulonglong2*)(mask + ((size_t)b * K + j) * 16);
#pragma unroll
        for (int t = 0; t < 8; t++) {
            ulonglong2 v = rp2[t];
            rw[2 * t] = v.x; rw[2 * t + 1] = v.y;
        }
#pragma unroll
        for (int t = 0; t < 16; t++) {
            unsigned long long bm =
                (t < w) ? ~0ull
                        : ((t == w && jb != 0) ? ((1ull << jb) - 1ull) : 0ull);
            rw[t] &= bm;                 // only i<j can suppress j
        }
    } else {
#pragma unroll
        for (int t = 0; t < 16; t++) rw[t] = 0ull;
    }
    if (j < 16) { U[j] = (j < 15) ? ~0ull : ((1ull << 40) - 1); L[j] = 0ull; }
    if (j == 0) { flag[0] = 0; flag[1] = 0; }
    __syncthreads();
    for (int k = 0; k < 1025; k++) {
        unsigned long long supU = 0ull, supL = 0ull;
#pragma unroll
        for (int t = 0; t < 16; t++) {
            unsigned long long Ut = U[t], Lt = L[t];   // broadcast (same addr)
            supU |= Lt & rw[t];   // new U = f(L)
            supL |= Ut & rw[t];   // new L = f(U)
        }
        bool nu = (j < K) && (supU == 0ull);
        bool nl = (j < K) && (supL == 0ull);
        __syncthreads();                     // all reads of old U/L done
        unsigned long long bu = __ballot(nu);
        unsigned long long bl = __ballot(nl);
        if (jb == 0) {
            U[w] = bu; L[w] = bl;
            if (bu != bl) flag[k & 1] = 1;
        }
        if (j == 0) flag[(k + 1) & 1] = 0;
        __syncthreads();
        if (flag[k & 1] == 0) break;         // uniform exit; U==L == exact keep
    }
    if (j < K) {
        bool kp = ((U[w] >> jb) & 1ull) != 0ull;
        kp = kp && (s >= 0.05f);
        ((float4*)(out + OFF_BOX))[b * K + j] = bb;
        out[OFF_SCORE + b * K + j] = kp ? s : 0.0f;
        out[OFF_KEEP + b * K + j]  = kp ? 1.0f : 0.0f;
    }
}

extern "C" void kernel_launch(void* const* d_in, const int* in_sizes, int n_in,
                              void* d_out, int out_size, void* d_ws, size_t ws_size,
                              hipStream_t stream) {
    const float* conf    = (const float*)d_in[0];
    const float* cls     = (const float*)d_in[1];
    const float* reg     = (const float*)d_in[2];
    const float* anchors = (const float*)d_in[3];
    float* out = (float*)d_out;
    char* ws = (char*)d_ws;

    unsigned long long* keys  = (unsigned long long*)(ws + WS_KEYS);
    int*                labels = (int*)(ws + WS_LABELS);
    unsigned long long* skeys = (unsigned long long*)(ws + WS_SKEYS);
    unsigned long long* mask  = (unsigned long long*)(ws + WS_MASK);

    k_scores<<<dim3(160, B), 256, 0, stream>>>(conf, cls, keys, labels);
    k_topk  <<<B, 1024, 0, stream>>>(keys, labels, skeys, out);
    k_mask  <<<dim3(34, B), 256, 0, stream>>>(skeys, labels, reg, anchors, mask);
    k_nms   <<<32, 1024, 0, stream>>>(mask, skeys, reg, anchors, out);
}

// Round 9
// 139.504 us; speedup vs baseline: 3.8955x; 1.0771x over previous
//
#include <hip/hip_runtime.h>
#include <cstdint>
#include <math.h>

// R8: attribution hybrid. R7 (+3.4 us regression) bundled two levers; cost
// model blames the decode relocation (~180 f64 ops/lane re-decode in k_mask
// + extra indirection), not the k_topk v3 sort. This round: R5 verbatim
// (k_scores, k_mask v2 with boxes_off, k_nms, decode_write, workspace)
// + ONLY k_topk v3's two-level radix refinement + N=1024 1-elem/thread
// bitonic, with R5's decode_write epilogue restored inside k_topk.
// Both halves individually verified (absmax 0.0 in R6/R7).
// Prediction: <=145 keep; ~147 wash; >=148 -> v3 was the regression,
// revert to R5 next round and assess roofline.

// Problem constants (from reference)
constexpr int B = 32;
constexpr int M = 5120;          // 32*32*5 anchors
constexpr int C = 80;            // classes
constexpr int K = 1000;          // TOPK

// d_out layout (flat float32, return order): scores | labels | bboxes | keep
constexpr int OFF_SCORE = 0;
constexpr int OFF_LAB   = B * K;            // 32000
constexpr int OFF_BOX   = 2 * B * K;        // 64000
constexpr int OFF_KEEP  = 2 * B * K + 4 * B * K; // 192000

// workspace layout (bytes) — R5 layout restored
constexpr size_t WS_KEYS     = 0;                                   // B*M u64
constexpr size_t WS_LABELS   = WS_KEYS   + (size_t)B * M * 8;       // B*M int
constexpr size_t WS_SELSC    = WS_LABELS + (size_t)B * M * 4;       // B*K f32
constexpr size_t WS_BOXOFF   = WS_SELSC + (size_t)B * K * 4;        // B*K*4 f32
constexpr size_t WS_MASK     = WS_BOXOFF + (size_t)B * K * 4 * 4;   // B*K*16 u64

// Fast f64 exp (R2, four-times verified absmax 0.0 on this dataset).
__device__ __forceinline__ double exp_fast(double t) {
    constexpr double INVLN2 = 1.4426950408889634074;
    constexpr double LN2HI  = 6.93147180369123816490e-01; // 33 sig bits
    constexpr double LN2LO  = 1.90821492927058770002e-10;
    double kd = rint(t * INVLN2);
    kd = fmin(fmax(kd, -1000.0), 1000.0);    // guard (no-op for valid data)
    int k = (int)kd;
    double r = (t - kd * LN2HI) - kd * LN2LO;   // first sub exact (Sterbenz)
    constexpr double C3 = 1.0/6.0,        C4  = 1.0/24.0,        C5  = 1.0/120.0;
    constexpr double C6 = 1.0/720.0,      C7  = 1.0/5040.0,      C8  = 1.0/40320.0;
    constexpr double C9 = 1.0/362880.0,   C10 = 1.0/3628800.0,   C11 = 1.0/39916800.0;
    constexpr double C12 = 1.0/479001600.0, C13 = 1.0/6227020800.0;
    double s = fma(r, C13, C12);
    s = fma(r, s, C11); s = fma(r, s, C10); s = fma(r, s, C9);
    s = fma(r, s, C8);  s = fma(r, s, C7);  s = fma(r, s, C6);
    s = fma(r, s, C5);  s = fma(r, s, C4);  s = fma(r, s, C3);
    double u = r * r;
    double q = fma(r, s, 0.5);
    double v = fma(u, q, r);
    double p = 1.0 + v;                       // in [0.707, 1.415]
    long long sbits = (long long)(1023 + k) << 52;
    return p * __longlong_as_double(sbits);   // exact 2^k scale
}
__device__ __forceinline__ float expf_cr(float x) {
    return (float)exp_fast((double)x);
}
__device__ __forceinline__ float sigm_np(float x) {
    float e = expf_cr(-x);
    return __fdiv_rn(1.0f, __fadd_rn(1.0f, e));
}

// Kernel 1: numpy-f32 score/label — 8 lanes per anchor (verified R5 body).
__global__ void __launch_bounds__(256)
k_scores(const float* __restrict__ conf, const float* __restrict__ cls,
         unsigned long long* __restrict__ keys, int* __restrict__ labels) {
    int b = blockIdx.y;                  // 0..31
    int g0 = blockIdx.x * 32;            // anchor base within batch (grid.x=160)
    int tid = threadIdx.x;               // 0..255 -> 32 anchors x 8 lanes
    __shared__ float s_lds[32];
    if (tid < 32) {                      // batch the 32 sigmoids (1 wave-exp)
        s_lds[tid] = sigm_np(conf[(size_t)b * M + g0 + tid]);
    }
    __syncthreads();
    int grp = tid >> 3;                  // anchor within block (0..31)
    int j   = tid & 7;                   // numpy column (0..7)
    int m = g0 + grp;
    size_t base = ((size_t)b * M + m) * C + j;
    float x[10];
#pragma unroll
    for (int k = 0; k < 10; k++) x[k] = cls[base + 8 * k];
    float mx = x[0];
#pragma unroll
    for (int k = 1; k < 10; k++) mx = fmaxf(mx, x[k]);
#pragma unroll
    for (int d = 1; d < 8; d <<= 1) mx = fmaxf(mx, __shfl_xor(mx, d, 64));
    float e[10];
#pragma unroll
    for (int k = 0; k < 10; k++) e[k] = expf_cr(__fsub_rn(x[k], mx));
    float r = e[0];
#pragma unroll
    for (int k = 1; k < 10; k++) r = __fadd_rn(r, e[k]);
    float t1  = __fadd_rn(r,  __shfl_xor(r, 1, 64));
    float t2  = __fadd_rn(t1, __shfl_xor(t1, 2, 64));
    float sum = __fadd_rn(t2, __shfl_xor(t2, 4, 64));
    float s = s_lds[grp];
    float best = -1.0f; int bc = 0;
#pragma unroll
    for (int k = 0; k < 10; k++) {
        float q = __fdiv_rn(e[k], sum);
        float p = __fmul_rn(s, q);
        if (p > best) { best = p; bc = 8 * k + j; }   // k asc => first max
    }
#pragma unroll
    for (int d = 1; d < 8; d <<= 1) {    // lattice max on (p, -c)
        float op = __shfl_xor(best, d, 64);
        int   oc = __shfl_xor(bc,   d, 64);
        if (op > best || (op == best && oc < bc)) { best = op; bc = oc; }
    }
    if (j == 0) {
        keys[(size_t)b * M + m] =
            ((unsigned long long)__float_as_uint(best) << 32) |
            (unsigned long long)(0xFFFFFFFFu - (unsigned)m);
        labels[(size_t)b * M + m] = bc;
    }
}

// Decode one selected box (numpy-f32 op order) and write all its outputs.
__device__ __forceinline__ void decode_write(
    int b, int rank, int m, float score, int lab,
    const float* __restrict__ reg, const float* __restrict__ anchors,
    float* __restrict__ out, float4* __restrict__ boxes_off,
    float* __restrict__ sel_score)
{
    float4 r = ((const float4*)reg)[(size_t)b * M + m];
    float4 a = ((const float4*)anchors)[m];
    float cx = __fadd_rn(__fmul_rn(sigm_np(r.x), 16.0f), a.x);
    float cy = __fadd_rn(__fmul_rn(sigm_np(r.y), 16.0f), a.y);
    float w  = __fmul_rn(expf_cr(r.z), a.z);
    float h  = __fmul_rn(expf_cr(r.w), a.w);
    float x1 = __fdiv_rn(__fsub_rn(cx, __fmul_rn(0.5f, w)), 512.0f);
    float y1 = __fdiv_rn(__fsub_rn(cy, __fmul_rn(0.5f, h)), 512.0f);
    float x2 = __fdiv_rn(__fadd_rn(cx, __fmul_rn(0.5f, w)), 512.0f);
    float y2 = __fdiv_rn(__fadd_rn(cy, __fmul_rn(0.5f, h)), 512.0f);
    x1 = fminf(fmaxf(x1, 0.0f), 1.0f);
    y1 = fminf(fmaxf(y1, 0.0f), 1.0f);
    x2 = fminf(fmaxf(x2, 0.0f), 1.0f);
    y2 = fminf(fmaxf(y2, 0.0f), 1.0f);
    ((float4*)(out + OFF_BOX))[b * K + rank] = make_float4(x1, y1, x2, y2);
    out[OFF_LAB + b * K + rank] = (float)lab;
    float off = __fmul_rn(2.0f, (float)lab);
    boxes_off[b * K + rank] = make_float4(__fadd_rn(x1, off), __fadd_rn(y1, off),
                                          __fadd_rn(x2, off), __fadd_rn(y2, off));
    sel_score[b * K + rank] = score;
}

// Register-bitonic compare-exchange (partner within wave, jsz<=32).
__device__ __forceinline__ void cx_reg(unsigned long long& v, int i, int jsz, int ksz) {
    unsigned long long vp = __shfl_xor(v, jsz, 64);
    bool takeMax = (((i & ksz) == 0) == ((i & jsz) == 0));
    v = takeMax ? (vp > v ? vp : v) : (vp < v ? vp : v);
}

// Kernel 2 v3-sel: exact top-K. Two-level radix threshold (S<=1024
// virtually always; overflow falls back to exact O(M) rank) + N=1024
// one-elem-per-thread bitonic. R5 decode_write epilogue (fused decode).
// Selection exactness: the refined predicate excludes only keys with
// (bin < T1) or (bin == T1 && subbin < T2); every excluded key is
// u64-less than every included key and included count >= K, so the
// top-K of the included set == global top-K.
__global__ void __launch_bounds__(1024)
k_topk(const unsigned long long* __restrict__ keys,
       const int* __restrict__ labels,
       const float* __restrict__ reg, const float* __restrict__ anchors,
       float* __restrict__ out, float4* __restrict__ boxes_off,
       float* __restrict__ sel_score) {
    int b = blockIdx.x;                  // grid = 32
    int tid = threadIdx.x;               // block = 1024
    int lane = tid & 63;
    int wv   = tid >> 6;                 // 16 waves
    const unsigned long long* kb = keys + (size_t)b * M;

    __shared__ unsigned int hist[2048];
    __shared__ unsigned long long cand[1024];   // 8 KB
    __shared__ unsigned int waveSuf[17];
    __shared__ int scnt, thrBin, thrBin2, sA, ovf;

    for (int i = tid; i < 2048; i += 1024) hist[i] = 0;
    if (tid == 0) { scnt = 0; ovf = 0; }
    __syncthreads();

    unsigned long long k5[5];
#pragma unroll
    for (int i = 0; i < 5; i++) {
        k5[i] = kb[tid + i * 1024];              // coalesced
        atomicAdd(&hist[(unsigned)(k5[i] >> 51)], 1u);
    }
    __syncthreads();

    // ---- level-1 hierarchical suffix scan (top 13 key bits) ----
    {
        unsigned h0 = hist[2 * tid], h1 = hist[2 * tid + 1];
        unsigned pr = h0 + h1;
        unsigned s = pr;
#pragma unroll
        for (int d = 1; d < 64; d <<= 1) {
            unsigned o = __shfl_down(s, d, 64);
            if (lane + d < 64) s += o;
        }
        if (lane == 0) waveSuf[wv] = s;
        if (tid == 0) waveSuf[16] = 0;
        __syncthreads();
        if (wv == 0) {
            unsigned t = (lane < 16) ? waveSuf[lane] : 0u;
#pragma unroll
            for (int d = 1; d < 16; d <<= 1) {
                unsigned o = __shfl_down(t, d, 64);
                if (lane + d < 64) t += o;
            }
            if (lane < 16) waveSuf[lane] = t;
        }
        __syncthreads();
        unsigned aboveWave = waveSuf[wv + 1];
        unsigned aboveLane = s - pr;
        unsigned suf1 = aboveWave + aboveLane + h1;
        unsigned suf0 = suf1 + h0;
        // unique crossing; crossing thread records A (count above bin T1)
        if (suf0 >= (unsigned)K && suf0 - h0 < (unsigned)K) {
            thrBin = 2 * tid; sA = (int)(suf0 - h0);
        }
        if (suf1 >= (unsigned)K && suf1 - h1 < (unsigned)K) {
            thrBin = 2 * tid + 1; sA = (int)(suf1 - h1);
        }
    }
    __syncthreads();
    int T1 = thrBin, A = sA;
    // refined iff level-1 candidate set would overflow the 1024 sort
    unsigned S1 = 0;
    {
        // S1 = A + H where H = hist[T1]; recompute cheaply via shared hist
        S1 = (unsigned)A + hist[T1];
    }
    bool refined = (S1 > 1024u);
    int T2 = 0;

    if (refined) {
        // ---- level-2: histogram bin-T1 members on key bits 50..40 ----
        __syncthreads();                     // done reading hist level-1
        for (int i = tid; i < 2048; i += 1024) hist[i] = 0;
        __syncthreads();
#pragma unroll
        for (int i = 0; i < 5; i++)
            if ((int)(k5[i] >> 51) == T1)
                atomicAdd(&hist[(unsigned)((k5[i] >> 40) & 2047)], 1u);
        __syncthreads();
        unsigned KK = (unsigned)(K - A);          // >0 since A<K
        unsigned g0 = hist[2 * tid], g1 = hist[2 * tid + 1];
        unsigned pr = g0 + g1;
        unsigned s = pr;
#pragma unroll
        for (int d = 1; d < 64; d <<= 1) {
            unsigned o = __shfl_down(s, d, 64);
            if (lane + d < 64) s += o;
        }
        if (lane == 0) waveSuf[wv] = s;
        if (tid == 0) waveSuf[16] = 0;
        __syncthreads();
        if (wv == 0) {
            unsigned t = (lane < 16) ? waveSuf[lane] : 0u;
#pragma unroll
            for (int d = 1; d < 16; d <<= 1) {
                unsigned o = __shfl_down(t, d, 64);
                if (lane + d < 64) t += o;
            }
            if (lane < 16) waveSuf[lane] = t;
        }
        __syncthreads();
        unsigned aboveWave = waveSuf[wv + 1];
        unsigned aboveLane = s - pr;
        unsigned suf1 = aboveWave + aboveLane + g1;
        unsigned suf0 = suf1 + g0;
        if (suf0 >= KK && suf0 - g0 < KK) thrBin2 = 2 * tid;
        if (suf1 >= KK && suf1 - g1 < KK) thrBin2 = 2 * tid + 1;
        __syncthreads();
        T2 = thrBin2;
    }

    // ---- collect candidates ----
#pragma unroll
    for (int i = 0; i < 5; i++) {
        int bin = (int)(k5[i] >> 51);
        bool sel = refined
                 ? (bin > T1 || (bin == T1 && (int)((k5[i] >> 40) & 2047) >= T2))
                 : (bin >= T1);
        if (sel) {
            int pos = atomicAdd(&scnt, 1);
            if (pos < 1024) cand[pos] = k5[i]; else ovf = 1;
        }
    }
    __syncthreads();

    if (!ovf) {
        int S = scnt;                        // K <= S <= 1024
        if (tid >= S) cand[tid] = 0ull;      // pad sorts below real keys (>0)
        __syncthreads();
        unsigned long long v = cand[tid];    // element index == tid
        // stages ksz=2..64: intra-wave, pure registers, 0 barriers
#pragma unroll
        for (int ksz = 2; ksz <= 64; ksz <<= 1)
#pragma unroll
            for (int jsz = ksz >> 1; jsz > 0; jsz >>= 1)
                cx_reg(v, tid, jsz, ksz);
        // stages ksz=128..1024: jsz>=64 via LDS exchange, jsz<=32 registers
        for (int ksz = 128; ksz <= 1024; ksz <<= 1) {
            for (int jsz = ksz >> 1; jsz >= 64; jsz >>= 1) {
                cand[tid] = v;
                __syncthreads();
                unsigned long long vp = cand[tid ^ jsz];
                bool takeMax = (((tid & ksz) == 0) == ((tid & jsz) == 0));
                v = takeMax ? (vp > v ? vp : v) : (vp < v ? vp : v);
                __syncthreads();
            }
#pragma unroll
            for (int jsz = 32; jsz > 0; jsz >>= 1)
                cx_reg(v, tid, jsz, ksz);
        }
        if (tid < K) {                       // v = key of rank tid
            int mm = (int)(0xFFFFFFFFu - (unsigned)(v & 0xFFFFFFFFu));
            float sc = __uint_as_float((unsigned)(v >> 32));
            int lab = labels[(size_t)b * M + mm];
            decode_write(b, tid, mm, sc, lab, reg, anchors, out, boxes_off, sel_score);
        }
    } else {
        // exact fallback (never expected): O(M) rank per key
#pragma unroll
        for (int i = 0; i < 5; i++) {
            unsigned long long my = k5[i];
            int rank = 0;
            for (int j = 0; j < M; j++) rank += (kb[j] > my) ? 1 : 0;
            if (rank < K) {
                int mm = tid + i * 1024;
                float sc = __uint_as_float((unsigned)(my >> 32));
                int lab = labels[(size_t)b * M + mm];
                decode_write(b, rank, mm, sc, lab, reg, anchors, out, boxes_off, sel_score);
            }
        }
    }
}

// Kernel 3 v2 (R5, verified): dense lower-triangle packing, wave-private
// LDS j-tile from boxes_off, exact f64 midpoint IoU test.
__global__ void __launch_bounds__(256)
k_mask(const float4* __restrict__ boxes_off,
       unsigned long long* __restrict__ mask) {
    int b    = blockIdx.y;               // 0..31
    int wv   = threadIdx.x >> 6;         // 0..3
    int lane = threadIdx.x & 63;
    int p = blockIdx.x * 4 + wv;         // 0..135 word-tile index
    // triangular decode: largest r with r(r+1)/2 <= p (+ integer fixup)
    int r = (int)((sqrtf((float)(8 * p + 1)) - 1.0f) * 0.5f);
    int tri = (r * (r + 1)) >> 1;
    if (tri > p)          { r -= 1; tri = (r * (r + 1)) >> 1; }
    else if (p - tri > r) { r += 1; tri = (r * (r + 1)) >> 1; }
    int W = p - tri;                     // 0..r

    __shared__ float4 sj[4][64];
    __shared__ float  sa[4][64];
    int j = W * 64 + lane;
    float4 bx = (j < K) ? boxes_off[b * K + j]
                        : make_float4(3e30f, 3e30f, -3e30f, -3e30f);
    sj[wv][lane] = bx;
    sa[wv][lane] = __fmul_rn(__fsub_rn(bx.z, bx.x), __fsub_rn(bx.w, bx.y));
    int i = r * 64 + lane;
    bool rowOk = (i < K);
    float4 bi = make_float4(0.f, 0.f, 0.f, 0.f);
    float ai = 0.f;
    if (rowOk) {
        bi = boxes_off[b * K + i];
        ai = __fmul_rn(__fsub_rn(bi.z, bi.x), __fsub_rn(bi.w, bi.y));
    }
    __syncthreads();
    if (!rowOk) return;
    // RN(inter/denom) > 0.6f <=> (double)inter > MID*(double)denom (exact;
    // MID = midpoint of [0.6f, succ(0.6f)], tie rounds to even = 0.6f).
    constexpr double MID = (double)0.6f + 0x1.0p-25;
    unsigned long long bits = 0ull;
#pragma unroll 8
    for (int jj = 0; jj < 64; jj++) {
        float4 bj = sj[wv][jj];          // wave-uniform -> broadcast
        float aj = sa[wv][jj];
        float xx1 = fmaxf(bi.x, bj.x), yy1 = fmaxf(bi.y, bj.y);
        float xx2 = fminf(bi.z, bj.z), yy2 = fminf(bi.w, bj.w);
        float ww = fmaxf(1e-28f, __fsub_rn(xx2, xx1));
        float hh = fmaxf(1e-28f, __fsub_rn(yy2, yy1));
        float inter = __fmul_rn(ww, hh);
        float denom = __fadd_rn(__fsub_rn(__fadd_rn(ai, aj), inter), 1e-14f);
        if ((double)inter > MID * (double)denom) bits |= (1ull << jj);
    }
    mask[((size_t)b * K + i) * 16 + W] = bits;
}

// Kernel 4 (R5, verified): exact NMS via bracketed Jacobi fixed point.
__global__ void __launch_bounds__(1024)
k_nms(const unsigned long long* __restrict__ mask,
      const float* __restrict__ sel_score,
      float* __restrict__ out) {
    int b = blockIdx.x;
    int j = threadIdx.x;                 // 0..1023
    int w = j >> 6;                      // wave index == keep-word index
    int jb = j & 63;
    __shared__ unsigned long long U[16], L[16];
    __shared__ int flag[2];
    unsigned long long rw[16];
    if (j < K) {
        const ulonglong2* rp2 =
            (const ulonglong2*)(mask + ((size_t)b * K + j) * 16);
#pragma unroll
        for (int t = 0; t < 8; t++) {
            ulonglong2 v = rp2[t];
            rw[2 * t] = v.x; rw[2 * t + 1] = v.y;
        }
#pragma unroll
        for (int t = 0; t < 16; t++) {
            unsigned long long bm =
                (t < w) ? ~0ull
                        : ((t == w && jb != 0) ? ((1ull << jb) - 1ull) : 0ull);
            rw[t] &= bm;                 // only i<j can suppress j
        }
    } else {
#pragma unroll
        for (int t = 0; t < 16; t++) rw[t] = 0ull;
    }
    if (j < 16) { U[j] = (j < 15) ? ~0ull : ((1ull << 40) - 1); L[j] = 0ull; }
    if (j == 0) { flag[0] = 0; flag[1] = 0; }
    __syncthreads();
    for (int k = 0; k < 1025; k++) {
        unsigned long long supU = 0ull, supL = 0ull;
#pragma unroll
        for (int t = 0; t < 16; t++) {
            unsigned long long Ut = U[t], Lt = L[t];   // broadcast (same addr)
            supU |= Lt & rw[t];   // new U = f(L)
            supL |= Ut & rw[t];   // new L = f(U)
        }
        bool nu = (j < K) && (supU == 0ull);
        bool nl = (j < K) && (supL == 0ull);
        __syncthreads();                     // all reads of old U/L done
        unsigned long long bu = __ballot(nu);
        unsigned long long bl = __ballot(nl);
        if (jb == 0) {
            U[w] = bu; L[w] = bl;
            if (bu != bl) flag[k & 1] = 1;
        }
        if (j == 0) flag[(k + 1) & 1] = 0;
        __syncthreads();
        if (flag[k & 1] == 0) break;         // uniform exit; U==L == exact keep
    }
    if (j < K) {
        bool kp = ((U[w] >> jb) & 1ull) != 0ull;
        float s = sel_score[b * K + j];
        kp = kp && (s >= 0.05f);
        out[OFF_SCORE + b * K + j] = kp ? s : 0.0f;
        out[OFF_KEEP + b * K + j]  = kp ? 1.0f : 0.0f;
    }
}

extern "C" void kernel_launch(void* const* d_in, const int* in_sizes, int n_in,
                              void* d_out, int out_size, void* d_ws, size_t ws_size,
                              hipStream_t stream) {
    const float* conf    = (const float*)d_in[0];
    const float* cls     = (const float*)d_in[1];
    const float* reg     = (const float*)d_in[2];
    const float* anchors = (const float*)d_in[3];
    float* out = (float*)d_out;
    char* ws = (char*)d_ws;

    unsigned long long* keys = (unsigned long long*)(ws + WS_KEYS);
    int*    labels   = (int*)(ws + WS_LABELS);
    float*  sel_sc   = (float*)(ws + WS_SELSC);
    float4* boxes_off = (float4*)(ws + WS_BOXOFF);
    unsigned long long* mask = (unsigned long long*)(ws + WS_MASK);

    k_scores<<<dim3(160, B), 256, 0, stream>>>(conf, cls, keys, labels);
    k_topk  <<<B, 1024, 0, stream>>>(keys, labels, reg, anchors, out, boxes_off, sel_sc);
    k_mask  <<<dim3(34, B), 256, 0, stream>>>(boxes_off, mask);
    k_nms   <<<32, 1024, 0, stream>>>(mask, sel_sc, out);
}